// Round 1
// 304.724 us; speedup vs baseline: 1.0776x; 1.0776x over previous
//
#include <hip/hip_runtime.h>

// Problem constants
#define NBANDS 64
#define LATENT 256
#define HIDDEN 512
#define GQ 8
#define KQ 1024
#define GD 32
#define NROWS 16000   // B*T = 16*1000

// d_out float offsets
#define OUT_BH   0
#define OUT_ZE   1024000
#define OUT_ZQ   5120000
#define OUT_IDX  9216000
#define OUT_LOSS 9344000

// ws float offsets.  H region [0,8192000) is live ONLY between enc1 and enc2;
// bf16 buffers overlay it and MUST be written after enc2.
#define WS_H     0
#define WS_H2BF_F  0
#define WS_ZQB_F   4096000
#define WS_W1B_F   6144000
#define WS_W2B_F   6209536
// 3-way bf16 split of codebooks (written by prep_wT, read by vq_mfma).
// 262144 ushort = 131072 floats each; all inside dead-H overlay region.
#define WS_CBH_F   6240000
#define WS_CBM_F   6400000
#define WS_CBL_F   6560000
#define WS_CN    8192000
#define WS_LOSS  8200192

typedef __attribute__((ext_vector_type(8))) short bf16x8;
typedef __attribute__((ext_vector_type(4))) float f32x4;

__device__ __forceinline__ unsigned short f2bf(float f) {
  unsigned u = __builtin_bit_cast(unsigned, f);
  unsigned r = u + 0x7FFFu + ((u >> 16) & 1u);   // RNE; inputs finite
  return (unsigned short)(r >> 16);
}

__device__ __forceinline__ float bf2f(unsigned short h) {
  return __builtin_bit_cast(float, ((unsigned)h) << 16);
}

// 3-way bf16 split: x ~= h + m + l with residual ~2^-24 |x|.
// x - RNE_bf16(x) is exact in fp32 (Sterbenz), so m/l capture the tail exactly.
__device__ __forceinline__ void split3(float x, unsigned short& h,
                                       unsigned short& m, unsigned short& l) {
  h = f2bf(x);
  const float r1 = x - bf2f(h);
  m = f2bf(r1);
  const float r2 = r1 - bf2f(m);
  l = f2bf(r2);
}

// ---------------------------------------------------------------------------
// fp32 GEMM, 128xBN tile, TMxTN microtile, templated BK, 256 threads.
// Ascending-k accumulation regardless of BK -> bit-identical results.
// ---------------------------------------------------------------------------
template<int BN, int TM, int TN, int BK, bool RELU>
__global__ __launch_bounds__(256) void gemm_f32(
    const float* __restrict__ A, const float* __restrict__ B,
    const float* __restrict__ bias, float* __restrict__ C,
    int M, int N, int K) {
  constexpr int BM = 128;
  constexpr int NTX = BN / TN;
  constexpr int AF4 = BK / 8;
  constexpr int QPR = BN / 4;
  constexpr int BF4 = BK * BN / 1024;

  __shared__ float As[BK][BM + 8];
  __shared__ float Bs[BK][BN + 4];

  const int tid = threadIdx.x;
  const int tx = tid % NTX;
  const int ty = tid / NTX;
  const int row0 = blockIdx.y * BM;
  const int col0 = blockIdx.x * BN;

  const int arow = tid >> 1;
  const int akq  = (tid & 1) * (BK / 2);

  float acc[TM][TN] = {};

  for (int k0 = 0; k0 < K; k0 += BK) {
    float4 av[AF4], bv[BF4];
#pragma unroll
    for (int q = 0; q < AF4; ++q)
      av[q] = *reinterpret_cast<const float4*>(
          &A[(size_t)(row0 + arow) * K + k0 + akq + q * 4]);
#pragma unroll
    for (int t = 0; t < BF4; ++t) {
      const int qq = tid * BF4 + t;
      const int bk = qq / QPR, bn4 = qq % QPR;
      bv[t] = *reinterpret_cast<const float4*>(
          &B[(size_t)(k0 + bk) * N + col0 + bn4 * 4]);
    }
    __syncthreads();
#pragma unroll
    for (int q = 0; q < AF4; ++q) {
      As[akq + q * 4 + 0][arow] = av[q].x;
      As[akq + q * 4 + 1][arow] = av[q].y;
      As[akq + q * 4 + 2][arow] = av[q].z;
      As[akq + q * 4 + 3][arow] = av[q].w;
    }
#pragma unroll
    for (int t = 0; t < BF4; ++t) {
      const int qq = tid * BF4 + t;
      const int bk = qq / QPR, bn4 = qq % QPR;
      *reinterpret_cast<float4*>(&Bs[bk][bn4 * 4]) = bv[t];
    }
    __syncthreads();

#pragma unroll
    for (int kk = 0; kk < BK; ++kk) {
      float a[TM], b[TN];
#pragma unroll
      for (int q = 0; q < TM / 4; ++q) {
        float4 v = *reinterpret_cast<const float4*>(&As[kk][ty * TM + q * 4]);
        a[q * 4 + 0] = v.x; a[q * 4 + 1] = v.y;
        a[q * 4 + 2] = v.z; a[q * 4 + 3] = v.w;
      }
#pragma unroll
      for (int q = 0; q < TN / 4; ++q) {
        float4 v = *reinterpret_cast<const float4*>(&Bs[kk][tx * TN + q * 4]);
        b[q * 4 + 0] = v.x; b[q * 4 + 1] = v.y;
        b[q * 4 + 2] = v.z; b[q * 4 + 3] = v.w;
      }
#pragma unroll
      for (int i = 0; i < TM; ++i)
#pragma unroll
        for (int j = 0; j < TN; ++j)
          acc[i][j] = fmaf(a[i], b[j], acc[i][j]);
    }
  }

  float bb[TN];
#pragma unroll
  for (int q = 0; q < TN / 4; ++q) {
    float4 v = *reinterpret_cast<const float4*>(&bias[col0 + tx * TN + q * 4]);
    bb[q * 4 + 0] = v.x; bb[q * 4 + 1] = v.y;
    bb[q * 4 + 2] = v.z; bb[q * 4 + 3] = v.w;
  }
#pragma unroll
  for (int i = 0; i < TM; ++i) {
    const int r = row0 + ty * TM + i;
#pragma unroll
    for (int q = 0; q < TN / 4; ++q) {
      float4 v;
      float* vp = &v.x;
#pragma unroll
      for (int j = 0; j < 4; ++j) {
        float t = acc[i][q * 4 + j] + bb[q * 4 + j];
        if (RELU) t = fmaxf(t, 0.0f);
        vp[j] = t;
      }
      *reinterpret_cast<float4*>(&C[(size_t)r * N + col0 + tx * TN + q * 4]) = v;
    }
  }
}

// ---------------------------------------------------------------------------
// bf16 MFMA GEMM with TRANSPOSED B (BT[n][k]) -> b128 B-staging.
// DO_LOSS: block(0,0) tid0 finalizes the vq loss scalar.
// ---------------------------------------------------------------------------
template<int WM, bool OUT_BF16, bool DO_LOSS>
__global__ __launch_bounds__(256) void gemm_bf16_mfma(
    const unsigned short* __restrict__ A, const unsigned short* __restrict__ BT,
    const float* __restrict__ bias, void* __restrict__ Cout,
    int M, int N, int K,
    const float* __restrict__ loss_acc, float* __restrict__ loss_out) {
  constexpr int BM = 4 * WM;
  constexpr int MT = WM / 16;

  __shared__ unsigned short As[BM][40];
  __shared__ unsigned short Bs[64][40];

  const int tid  = threadIdx.x;
  const int wave = tid >> 6;
  const int lane = tid & 63;
  const int quad = lane >> 4;
  const int l16  = lane & 15;
  const int row0 = blockIdx.y * BM;
  const int col0 = blockIdx.x * 64;

  if (DO_LOSS && blockIdx.x == 0 && blockIdx.y == 0 && tid == 0)
    loss_out[0] = 0.5f * loss_acc[0] / (float)((size_t)NROWS * GD);

  f32x4 acc[MT][4];
#pragma unroll
  for (int mt = 0; mt < MT; ++mt)
#pragma unroll
    for (int nt = 0; nt < 4; ++nt) acc[mt][nt] = (f32x4){0.f, 0.f, 0.f, 0.f};

  for (int k0 = 0; k0 < K; k0 += 32) {
    __syncthreads();
    if constexpr (BM == 128) {
      const int r = tid >> 1, seg = (tid & 1) * 16;
      const uint4* src = reinterpret_cast<const uint4*>(
          &A[(size_t)(row0 + r) * K + k0 + seg]);
      uint4* dst = reinterpret_cast<uint4*>(&As[r][seg]);
      dst[0] = src[0]; dst[1] = src[1];
    } else {
      const int r = tid >> 2, seg = (tid & 3) * 8;
      *reinterpret_cast<uint4*>(&As[r][seg]) =
          *reinterpret_cast<const uint4*>(&A[(size_t)(row0 + r) * K + k0 + seg]);
    }
    {
      const int n = tid >> 2, kc = (tid & 3) * 8;
      *reinterpret_cast<uint4*>(&Bs[n][kc]) =
          *reinterpret_cast<const uint4*>(&BT[(size_t)(col0 + n) * K + k0 + kc]);
    }
    __syncthreads();

    bf16x8 af[MT], bf[4];
#pragma unroll
    for (int mt = 0; mt < MT; ++mt)
      af[mt] = *reinterpret_cast<const bf16x8*>(
          &As[wave * WM + mt * 16 + l16][quad * 8]);
#pragma unroll
    for (int nt = 0; nt < 4; ++nt)
      bf[nt] = *reinterpret_cast<const bf16x8*>(&Bs[nt * 16 + l16][quad * 8]);
#pragma unroll
    for (int mt = 0; mt < MT; ++mt)
#pragma unroll
      for (int nt = 0; nt < 4; ++nt)
        acc[mt][nt] = __builtin_amdgcn_mfma_f32_16x16x32_bf16(
            af[mt], bf[nt], acc[mt][nt], 0, 0, 0);
  }

#pragma unroll
  for (int mt = 0; mt < MT; ++mt)
#pragma unroll
    for (int nt = 0; nt < 4; ++nt) {
      const int col = col0 + nt * 16 + l16;
      const float bv = bias[col];
#pragma unroll
      for (int r = 0; r < 4; ++r) {
        const int grow = row0 + wave * WM + mt * 16 + quad * 4 + r;
        float v = acc[mt][nt][r] + bv;
        if constexpr (OUT_BF16) {
          v = fmaxf(v, 0.0f);
          ((unsigned short*)Cout)[(size_t)grow * N + col] = f2bf(v);
        } else {
          ((float*)Cout)[(size_t)grow * N + col] = v;
        }
      }
    }
}

// ---------------------------------------------------------------------------
// prep_cn: cn = -0.5*||codebook||^2 (MFMA-accumulator seed for argmax form)
// + zero loss accumulator.  Runs FIRST.
// ---------------------------------------------------------------------------
__global__ void prep_cn(const float* __restrict__ cb, float* __restrict__ cn,
                        float* __restrict__ loss_acc) {
  const int i = blockIdx.x * 256 + threadIdx.x;
  if (i == 0) loss_acc[0] = 0.0f;
  if (i < GQ * KQ) {
    const float* c = cb + (size_t)i * GD;
    float s = 0.0f;
#pragma unroll
    for (int d = 0; d < GD; ++d) s = fmaf(c[d], c[d], s);
    cn[i] = -0.5f * s;
  }
}

// ---------------------------------------------------------------------------
// prep_wT: decoder weights -> TRANSPOSED bf16 (w1bT[n*256+k], w2bT[n*512+k])
// + codebook -> 3-way bf16 split (cbh/cbm/cbl) for the fp32-accurate VQ MFMA.
// MUST run after enc2 (all outputs overlay the then-dead fp32 H region).
// ---------------------------------------------------------------------------
__global__ void prep_wT(const float* __restrict__ w1, const float* __restrict__ w2,
                        const float* __restrict__ cbk,
                        unsigned short* __restrict__ w1bT,
                        unsigned short* __restrict__ w2bT,
                        unsigned short* __restrict__ cbh,
                        unsigned short* __restrict__ cbm,
                        unsigned short* __restrict__ cbl) {
  const int t = blockIdx.x * 256 + threadIdx.x;
  if (t < 16384) {                       // w1: [256 k][512 n] -> w1bT[n][k]
    const int n = t >> 5, k0 = (t & 31) * 8;
    alignas(16) unsigned short o[8];
#pragma unroll
    for (int q = 0; q < 8; ++q) o[q] = f2bf(w1[(size_t)(k0 + q) * HIDDEN + n]);
    *reinterpret_cast<uint4*>(&w1bT[(size_t)n * LATENT + k0]) =
        *reinterpret_cast<const uint4*>(o);
  } else if (t < 20480) {                // w2: [512 k][64 n] -> w2bT[n][k]
    const int u = t - 16384;
    const int n = u >> 6, k0 = (u & 63) * 8;
    alignas(16) unsigned short o[8];
#pragma unroll
    for (int q = 0; q < 8; ++q) o[q] = f2bf(w2[(size_t)(k0 + q) * NBANDS + n]);
    *reinterpret_cast<uint4*>(&w2bT[(size_t)n * HIDDEN + k0]) =
        *reinterpret_cast<const uint4*>(o);
  } else if (t < 53248) {                // codebook 3-way bf16 split, 8 elems/thread
    const int e0 = (t - 20480) * 8;
    alignas(16) unsigned short oh[8], om[8], ol[8];
#pragma unroll
    for (int q = 0; q < 8; ++q) split3(cbk[e0 + q], oh[q], om[q], ol[q]);
    *reinterpret_cast<uint4*>(&cbh[e0]) = *reinterpret_cast<const uint4*>(oh);
    *reinterpret_cast<uint4*>(&cbm[e0]) = *reinterpret_cast<const uint4*>(om);
    *reinterpret_cast<uint4*>(&cbl[e0]) = *reinterpret_cast<const uint4*>(ol);
  }
}

// ---------------------------------------------------------------------------
// vq_mfma: VQ nearest-codebook search on the MATRIX pipe.
//
// cross[n][k] = z.c computed via 3-way bf16 split (6 MFMAs: hh,hm,mh,hl,mm,lh)
// -> error ~2^-24 |z||c| per product, fp32-class -> argmin indices safe.
// K = GD = 32 -> exactly ONE mfma_f32_16x16x32_bf16 k-step per product tier.
//
// score = -0.5*||c||^2 + cross  (seeded via accumulator C-in; dist = -2*score)
// -> argMIN dist == argMAX score, zero per-distance epilogue FLOPs.
//
// No LDS, no barriers: A frags lane-private, B frags straight from the
// pre-split codebooks (128KB/group, L1/L2-hot: consecutive blockIdx.x share g),
// argmin reduced across the 16 l16-lanes by shfl_xor.
//
// Block: 256 thr = 4 waves x 32 rows = 128 rows; grid (125, 8 groups).
// Per wave: 16 chunks x 4 ntiles x (2 row-tiles x 6 MFMA) = 768 MFMA.
// ---------------------------------------------------------------------------
__global__ __launch_bounds__(256) void vq_mfma(
    const float* __restrict__ z_e, const float* __restrict__ cb,
    const float* __restrict__ cnh,           // = -0.5*||c||^2
    const unsigned short* __restrict__ cbh,
    const unsigned short* __restrict__ cbm,
    const unsigned short* __restrict__ cbl,
    float* __restrict__ z_q, unsigned short* __restrict__ zqb,
    float* __restrict__ idx_out, float* __restrict__ loss_acc) {
  const int g    = blockIdx.y;
  const int row0 = blockIdx.x * 128;
  const int tid  = threadIdx.x;
  const int wave = tid >> 6;
  const int lane = tid & 63;
  const int quad = lane >> 4;
  const int l16  = lane & 15;

  // ---- A fragments: rows wave*32 + mt*16 + l16, dims quad*8..+8 (in-reg split)
  bf16x8 ah[2], am[2], al[2];
#pragma unroll
  for (int mt = 0; mt < 2; ++mt) {
    const float* zp = &z_e[(size_t)(row0 + wave * 32 + mt * 16 + l16) * LATENT
                           + g * GD + quad * 8];
    const float4 x0 = *reinterpret_cast<const float4*>(zp);
    const float4 x1 = *reinterpret_cast<const float4*>(zp + 4);
    const float xv[8] = {x0.x, x0.y, x0.z, x0.w, x1.x, x1.y, x1.z, x1.w};
    bf16x8 vh, vm, vl;
#pragma unroll
    for (int j = 0; j < 8; ++j) {
      unsigned short sh, sm, sl;
      split3(xv[j], sh, sm, sl);
      vh[j] = (short)sh; vm[j] = (short)sm; vl[j] = (short)sl;
    }
    ah[mt] = vh; am[mt] = vm; al[mt] = vl;
  }

  const size_t cb0 = (size_t)g * KQ * GD;
  const float* cng = cnh + g * KQ;

  float best[8];
  int   bidx[8];
#pragma unroll
  for (int i = 0; i < 8; ++i) { best[i] = -3.0e38f; bidx[i] = 0; }

#pragma unroll 2
  for (int ch = 0; ch < 16; ++ch) {
#pragma unroll
    for (int nt = 0; nt < 4; ++nt) {
      const int code = ch * 64 + nt * 16 + l16;          // per-lane, ascending
      const size_t cba = cb0 + (size_t)code * GD + quad * 8;
      const bf16x8 bh = *reinterpret_cast<const bf16x8*>(&cbh[cba]);
      const bf16x8 bm = *reinterpret_cast<const bf16x8*>(&cbm[cba]);
      const bf16x8 bl = *reinterpret_cast<const bf16x8*>(&cbl[cba]);
      const float c0 = cng[code];
      f32x4 a0 = {c0, c0, c0, c0};                       // seed with -0.5||c||^2
      f32x4 a1 = a0;
      a0 = __builtin_amdgcn_mfma_f32_16x16x32_bf16(ah[0], bh, a0, 0, 0, 0);
      a1 = __builtin_amdgcn_mfma_f32_16x16x32_bf16(ah[1], bh, a1, 0, 0, 0);
      a0 = __builtin_amdgcn_mfma_f32_16x16x32_bf16(ah[0], bm, a0, 0, 0, 0);
      a1 = __builtin_amdgcn_mfma_f32_16x16x32_bf16(ah[1], bm, a1, 0, 0, 0);
      a0 = __builtin_amdgcn_mfma_f32_16x16x32_bf16(am[0], bh, a0, 0, 0, 0);
      a1 = __builtin_amdgcn_mfma_f32_16x16x32_bf16(am[1], bh, a1, 0, 0, 0);
      a0 = __builtin_amdgcn_mfma_f32_16x16x32_bf16(ah[0], bl, a0, 0, 0, 0);
      a1 = __builtin_amdgcn_mfma_f32_16x16x32_bf16(ah[1], bl, a1, 0, 0, 0);
      a0 = __builtin_amdgcn_mfma_f32_16x16x32_bf16(am[0], bm, a0, 0, 0, 0);
      a1 = __builtin_amdgcn_mfma_f32_16x16x32_bf16(am[1], bm, a1, 0, 0, 0);
      a0 = __builtin_amdgcn_mfma_f32_16x16x32_bf16(al[0], bh, a0, 0, 0, 0);
      a1 = __builtin_amdgcn_mfma_f32_16x16x32_bf16(al[1], bh, a1, 0, 0, 0);
      // argmax update; strict > keeps first (lowest) code on exact ties
#pragma unroll
      for (int r = 0; r < 4; ++r) {
        if (a0[r] > best[r])     { best[r] = a0[r];     bidx[r] = code; }
        if (a1[r] > best[4 + r]) { best[4 + r] = a1[r]; bidx[4 + r] = code; }
      }
    }
  }

  // ---- per-row reduce across the 16 l16-lanes (codes == l16 mod 16), then
  // 16 lanes cooperate on the 32-dim epilogue (2 dims each).
  float sse_local = 0.0f;
#pragma unroll
  for (int s8 = 0; s8 < 8; ++s8) {
    float mb = best[s8];
    int   mi = bidx[s8];
#pragma unroll
    for (int m = 1; m < 16; m <<= 1) {
      const float ov = __shfl_xor(mb, m, 64);
      const int   oi = __shfl_xor(mi, m, 64);
      if (ov > mb || (ov == mb && oi < mi)) { mb = ov; mi = oi; }
    }
    // all 16 lanes of this quad-group now agree on (mb, mi)
    const int mt  = s8 >> 2;
    const int r   = s8 & 3;
    const int row = row0 + wave * 32 + mt * 16 + quad * 4 + r;
    const float2 cw = *reinterpret_cast<const float2*>(
        &cb[cb0 + (size_t)mi * GD + 2 * l16]);
    const float2 zv = *reinterpret_cast<const float2*>(
        &z_e[(size_t)row * LATENT + g * GD + 2 * l16]);
    const float d0 = cw.x - zv.x;
    const float d1 = cw.y - zv.y;
    sse_local = fmaf(d0, d0, fmaf(d1, d1, sse_local));
    *reinterpret_cast<float2*>(
        &z_q[(size_t)row * LATENT + g * GD + 2 * l16]) = cw;
    const unsigned pz = (unsigned)f2bf(cw.x) | ((unsigned)f2bf(cw.y) << 16);
    *reinterpret_cast<unsigned*>(
        &zqb[(size_t)row * LATENT + g * GD + 2 * l16]) = pz;
    if (l16 == 0) idx_out[(size_t)row * GQ + g] = (float)mi;
  }

#pragma unroll
  for (int m = 1; m < 64; m <<= 1) sse_local += __shfl_xor(sse_local, m, 64);
  if (lane == 0) atomicAdd(loss_acc, sse_local);
}

// ---------------------------------------------------------------------------
extern "C" void kernel_launch(void* const* d_in, const int* in_sizes, int n_in,
                              void* d_out, int out_size, void* d_ws, size_t ws_size,
                              hipStream_t stream) {
  const float* bands  = (const float*)d_in[0];
  const float* enc_w1 = (const float*)d_in[1];
  const float* enc_b1 = (const float*)d_in[2];
  const float* enc_w2 = (const float*)d_in[3];
  const float* enc_b2 = (const float*)d_in[4];
  const float* cbooks = (const float*)d_in[5];
  const float* dec_w1 = (const float*)d_in[6];
  const float* dec_b1 = (const float*)d_in[7];
  const float* dec_w2 = (const float*)d_in[8];
  const float* dec_b2 = (const float*)d_in[9];

  float* out = (float*)d_out;
  float* ws  = (float*)d_ws;

  float* bands_hat = out + OUT_BH;
  float* z_e       = out + OUT_ZE;
  float* z_q       = out + OUT_ZQ;
  float* idx_f     = out + OUT_IDX;
  float* loss_out  = out + OUT_LOSS;

  float* H        = ws + WS_H;
  float* cn       = ws + WS_CN;
  float* loss_acc = ws + WS_LOSS;
  unsigned short* h2bf = (unsigned short*)(ws + WS_H2BF_F);
  unsigned short* zqb  = (unsigned short*)(ws + WS_ZQB_F);
  unsigned short* w1bT = (unsigned short*)(ws + WS_W1B_F);
  unsigned short* w2bT = (unsigned short*)(ws + WS_W2B_F);
  unsigned short* cbh  = (unsigned short*)(ws + WS_CBH_F);
  unsigned short* cbm  = (unsigned short*)(ws + WS_CBM_F);
  unsigned short* cbl  = (unsigned short*)(ws + WS_CBL_F);

  // cn (= -0.5||c||^2) + loss zero (safe: outside H region)
  prep_cn<<<dim3(32), dim3(256), 0, stream>>>(cbooks, cn, loss_acc);

  // Encoder (fp32): H = relu(bands@W1+b1); z_e = H@W2+b2 (enc2 BK=32)
  gemm_f32<128, 8, 8, 16, true ><<<dim3(HIDDEN / 128, NROWS / 128), dim3(256), 0, stream>>>(
      bands, enc_w1, enc_b1, H, NROWS, HIDDEN, NBANDS);
  gemm_f32<64, 4, 8, 32, false><<<dim3(LATENT / 64, NROWS / 128), dim3(256), 0, stream>>>(
      H, enc_w2, enc_b2, z_e, NROWS, LATENT, HIDDEN);

  // Decoder weights -> transposed bf16; codebook -> 3-way bf16 split
  // (H is dead now; overlays are safe)
  prep_wT<<<dim3(208), dim3(256), 0, stream>>>(
      dec_w1, dec_w2, cbooks, w1bT, w2bT, cbh, cbm, cbl);

  // VQ on the matrix pipe (fp32-class accuracy via 6-MFMA split)
  vq_mfma<<<dim3(NROWS / 128, GQ), dim3(256), 0, stream>>>(
      z_e, cbooks, cn, cbh, cbm, cbl, z_q, zqb, idx_f, loss_acc);

  // Decoder (bf16 MFMA, transposed-weight staging); dec1 finalizes loss
  gemm_bf16_mfma<32, true, true ><<<dim3(HIDDEN / 64, NROWS / 128), dim3(256), 0, stream>>>(
      zqb, w1bT, dec_b1, (void*)h2bf, NROWS, HIDDEN, LATENT, loss_acc, loss_out);
  gemm_bf16_mfma<16, false, false><<<dim3(NBANDS / 64, NROWS / 64), dim3(256), 0, stream>>>(
      h2bf, w2bT, dec_b2, (void*)bands_hat, NROWS, NBANDS, HIDDEN, loss_acc, loss_out);
}

// Round 3
// 294.032 us; speedup vs baseline: 1.1168x; 1.0364x over previous
//
#include <hip/hip_runtime.h>

// Problem constants
#define NBANDS 64
#define LATENT 256
#define HIDDEN 512
#define GQ 8
#define KQ 1024
#define GD 32
#define NROWS 16000   // B*T = 16*1000

// d_out float offsets
#define OUT_BH   0
#define OUT_ZE   1024000
#define OUT_ZQ   5120000
#define OUT_IDX  9216000
#define OUT_LOSS 9344000

// ws float offsets.  H region [0,8192000) is live ONLY between enc1 and enc2;
// bf16 buffers overlay it and MUST be written after enc2.
#define WS_H     0
#define WS_H2BF_F  0
#define WS_ZQB_F   4096000
#define WS_W1B_F   6144000
#define WS_W2B_F   6209536
// 3-way bf16 split of codebooks (written by prep_wT, read by vq_mfma).
// 262144 ushort = 131072 floats each; all inside dead-H overlay region.
#define WS_CBH_F   6240000
#define WS_CBM_F   6400000
#define WS_CBL_F   6560000
#define WS_CN    8192000
#define WS_LOSS  8200192

typedef __attribute__((ext_vector_type(8))) short bf16x8;
typedef __attribute__((ext_vector_type(4))) float f32x4;

__device__ __forceinline__ unsigned short f2bf(float f) {
  unsigned u = __builtin_bit_cast(unsigned, f);
  unsigned r = u + 0x7FFFu + ((u >> 16) & 1u);   // RNE; inputs finite
  return (unsigned short)(r >> 16);
}

__device__ __forceinline__ float bf2f(unsigned short h) {
  return __builtin_bit_cast(float, ((unsigned)h) << 16);
}

// 3-way bf16 split: x ~= h + m + l with residual ~2^-24 |x|.
__device__ __forceinline__ void split3(float x, unsigned short& h,
                                       unsigned short& m, unsigned short& l) {
  h = f2bf(x);
  const float r1 = x - bf2f(h);
  m = f2bf(r1);
  const float r2 = r1 - bf2f(m);
  l = f2bf(r2);
}

// ---------------------------------------------------------------------------
// fp32 GEMM, 128xBN tile, TMxTN microtile, templated BK, 256 threads.
// Ascending-k accumulation regardless of BK -> bit-identical results.
// ---------------------------------------------------------------------------
template<int BN, int TM, int TN, int BK, bool RELU>
__global__ __launch_bounds__(256) void gemm_f32(
    const float* __restrict__ A, const float* __restrict__ B,
    const float* __restrict__ bias, float* __restrict__ C,
    int M, int N, int K) {
  constexpr int BM = 128;
  constexpr int NTX = BN / TN;
  constexpr int AF4 = BK / 8;
  constexpr int QPR = BN / 4;
  constexpr int BF4 = BK * BN / 1024;

  __shared__ float As[BK][BM + 8];
  __shared__ float Bs[BK][BN + 4];

  const int tid = threadIdx.x;
  const int tx = tid % NTX;
  const int ty = tid / NTX;
  const int row0 = blockIdx.y * BM;
  const int col0 = blockIdx.x * BN;

  const int arow = tid >> 1;
  const int akq  = (tid & 1) * (BK / 2);

  float acc[TM][TN] = {};

  for (int k0 = 0; k0 < K; k0 += BK) {
    float4 av[AF4], bv[BF4];
#pragma unroll
    for (int q = 0; q < AF4; ++q)
      av[q] = *reinterpret_cast<const float4*>(
          &A[(size_t)(row0 + arow) * K + k0 + akq + q * 4]);
#pragma unroll
    for (int t = 0; t < BF4; ++t) {
      const int qq = tid * BF4 + t;
      const int bk = qq / QPR, bn4 = qq % QPR;
      bv[t] = *reinterpret_cast<const float4*>(
          &B[(size_t)(k0 + bk) * N + col0 + bn4 * 4]);
    }
    __syncthreads();
#pragma unroll
    for (int q = 0; q < AF4; ++q) {
      As[akq + q * 4 + 0][arow] = av[q].x;
      As[akq + q * 4 + 1][arow] = av[q].y;
      As[akq + q * 4 + 2][arow] = av[q].z;
      As[akq + q * 4 + 3][arow] = av[q].w;
    }
#pragma unroll
    for (int t = 0; t < BF4; ++t) {
      const int qq = tid * BF4 + t;
      const int bk = qq / QPR, bn4 = qq % QPR;
      *reinterpret_cast<float4*>(&Bs[bk][bn4 * 4]) = bv[t];
    }
    __syncthreads();

#pragma unroll
    for (int kk = 0; kk < BK; ++kk) {
      float a[TM], b[TN];
#pragma unroll
      for (int q = 0; q < TM / 4; ++q) {
        float4 v = *reinterpret_cast<const float4*>(&As[kk][ty * TM + q * 4]);
        a[q * 4 + 0] = v.x; a[q * 4 + 1] = v.y;
        a[q * 4 + 2] = v.z; a[q * 4 + 3] = v.w;
      }
#pragma unroll
      for (int q = 0; q < TN / 4; ++q) {
        float4 v = *reinterpret_cast<const float4*>(&Bs[kk][tx * TN + q * 4]);
        b[q * 4 + 0] = v.x; b[q * 4 + 1] = v.y;
        b[q * 4 + 2] = v.z; b[q * 4 + 3] = v.w;
      }
#pragma unroll
      for (int i = 0; i < TM; ++i)
#pragma unroll
        for (int j = 0; j < TN; ++j)
          acc[i][j] = fmaf(a[i], b[j], acc[i][j]);
    }
  }

  float bb[TN];
#pragma unroll
  for (int q = 0; q < TN / 4; ++q) {
    float4 v = *reinterpret_cast<const float4*>(&bias[col0 + tx * TN + q * 4]);
    bb[q * 4 + 0] = v.x; bb[q * 4 + 1] = v.y;
    bb[q * 4 + 2] = v.z; bb[q * 4 + 3] = v.w;
  }
#pragma unroll
  for (int i = 0; i < TM; ++i) {
    const int r = row0 + ty * TM + i;
#pragma unroll
    for (int q = 0; q < TN / 4; ++q) {
      float4 v;
      float* vp = &v.x;
#pragma unroll
      for (int j = 0; j < 4; ++j) {
        float t = acc[i][q * 4 + j] + bb[q * 4 + j];
        if (RELU) t = fmaxf(t, 0.0f);
        vp[j] = t;
      }
      *reinterpret_cast<float4*>(&C[(size_t)r * N + col0 + tx * TN + q * 4]) = v;
    }
  }
}

// ---------------------------------------------------------------------------
// bf16 MFMA GEMM with TRANSPOSED B (BT[n][k]) -> b128 B-staging.
// DO_LOSS: block(0,0) tid0 finalizes the vq loss scalar.
// ---------------------------------------------------------------------------
template<int WM, bool OUT_BF16, bool DO_LOSS>
__global__ __launch_bounds__(256) void gemm_bf16_mfma(
    const unsigned short* __restrict__ A, const unsigned short* __restrict__ BT,
    const float* __restrict__ bias, void* __restrict__ Cout,
    int M, int N, int K,
    const float* __restrict__ loss_acc, float* __restrict__ loss_out) {
  constexpr int BM = 4 * WM;
  constexpr int MT = WM / 16;

  __shared__ unsigned short As[BM][40];
  __shared__ unsigned short Bs[64][40];

  const int tid  = threadIdx.x;
  const int wave = tid >> 6;
  const int lane = tid & 63;
  const int quad = lane >> 4;
  const int l16  = lane & 15;
  const int row0 = blockIdx.y * BM;
  const int col0 = blockIdx.x * 64;

  if (DO_LOSS && blockIdx.x == 0 && blockIdx.y == 0 && tid == 0)
    loss_out[0] = 0.5f * loss_acc[0] / (float)((size_t)NROWS * GD);

  f32x4 acc[MT][4];
#pragma unroll
  for (int mt = 0; mt < MT; ++mt)
#pragma unroll
    for (int nt = 0; nt < 4; ++nt) acc[mt][nt] = (f32x4){0.f, 0.f, 0.f, 0.f};

  for (int k0 = 0; k0 < K; k0 += 32) {
    __syncthreads();
    if constexpr (BM == 128) {
      const int r = tid >> 1, seg = (tid & 1) * 16;
      const uint4* src = reinterpret_cast<const uint4*>(
          &A[(size_t)(row0 + r) * K + k0 + seg]);
      uint4* dst = reinterpret_cast<uint4*>(&As[r][seg]);
      dst[0] = src[0]; dst[1] = src[1];
    } else {
      const int r = tid >> 2, seg = (tid & 3) * 8;
      *reinterpret_cast<uint4*>(&As[r][seg]) =
          *reinterpret_cast<const uint4*>(&A[(size_t)(row0 + r) * K + k0 + seg]);
    }
    {
      const int n = tid >> 2, kc = (tid & 3) * 8;
      *reinterpret_cast<uint4*>(&Bs[n][kc]) =
          *reinterpret_cast<const uint4*>(&BT[(size_t)(col0 + n) * K + k0 + kc]);
    }
    __syncthreads();

    bf16x8 af[MT], bf[4];
#pragma unroll
    for (int mt = 0; mt < MT; ++mt)
      af[mt] = *reinterpret_cast<const bf16x8*>(
          &As[wave * WM + mt * 16 + l16][quad * 8]);
#pragma unroll
    for (int nt = 0; nt < 4; ++nt)
      bf[nt] = *reinterpret_cast<const bf16x8*>(&Bs[nt * 16 + l16][quad * 8]);
#pragma unroll
    for (int mt = 0; mt < MT; ++mt)
#pragma unroll
      for (int nt = 0; nt < 4; ++nt)
        acc[mt][nt] = __builtin_amdgcn_mfma_f32_16x16x32_bf16(
            af[mt], bf[nt], acc[mt][nt], 0, 0, 0);
  }

#pragma unroll
  for (int mt = 0; mt < MT; ++mt)
#pragma unroll
    for (int nt = 0; nt < 4; ++nt) {
      const int col = col0 + nt * 16 + l16;
      const float bv = bias[col];
#pragma unroll
      for (int r = 0; r < 4; ++r) {
        const int grow = row0 + wave * WM + mt * 16 + quad * 4 + r;
        float v = acc[mt][nt][r] + bv;
        if constexpr (OUT_BF16) {
          v = fmaxf(v, 0.0f);
          ((unsigned short*)Cout)[(size_t)grow * N + col] = f2bf(v);
        } else {
          ((float*)Cout)[(size_t)grow * N + col] = v;
        }
      }
    }
}

// ---------------------------------------------------------------------------
// prep_cn: cn = -0.5*||codebook||^2 (MFMA-accumulator seed for argmax form)
// + zero loss accumulator.  Runs FIRST.
// ---------------------------------------------------------------------------
__global__ void prep_cn(const float* __restrict__ cb, float* __restrict__ cn,
                        float* __restrict__ loss_acc) {
  const int i = blockIdx.x * 256 + threadIdx.x;
  if (i == 0) loss_acc[0] = 0.0f;
  if (i < GQ * KQ) {
    const float* c = cb + (size_t)i * GD;
    float s = 0.0f;
#pragma unroll
    for (int d = 0; d < GD; ++d) s = fmaf(c[d], c[d], s);
    cn[i] = -0.5f * s;
  }
}

// ---------------------------------------------------------------------------
// prep_wT: decoder weights -> TRANSPOSED bf16 (w1bT, w2bT)
// + codebook -> 3-way bf16 split (cbh/cbm/cbl) for the fp32-accurate VQ MFMA.
// MUST run after enc2 (all outputs overlay the then-dead fp32 H region).
// ---------------------------------------------------------------------------
__global__ void prep_wT(const float* __restrict__ w1, const float* __restrict__ w2,
                        const float* __restrict__ cbk,
                        unsigned short* __restrict__ w1bT,
                        unsigned short* __restrict__ w2bT,
                        unsigned short* __restrict__ cbh,
                        unsigned short* __restrict__ cbm,
                        unsigned short* __restrict__ cbl) {
  const int t = blockIdx.x * 256 + threadIdx.x;
  if (t < 16384) {                       // w1: [256 k][512 n] -> w1bT[n][k]
    const int n = t >> 5, k0 = (t & 31) * 8;
    alignas(16) unsigned short o[8];
#pragma unroll
    for (int q = 0; q < 8; ++q) o[q] = f2bf(w1[(size_t)(k0 + q) * HIDDEN + n]);
    *reinterpret_cast<uint4*>(&w1bT[(size_t)n * LATENT + k0]) =
        *reinterpret_cast<const uint4*>(o);
  } else if (t < 20480) {                // w2: [512 k][64 n] -> w2bT[n][k]
    const int u = t - 16384;
    const int n = u >> 6, k0 = (u & 63) * 8;
    alignas(16) unsigned short o[8];
#pragma unroll
    for (int q = 0; q < 8; ++q) o[q] = f2bf(w2[(size_t)(k0 + q) * NBANDS + n]);
    *reinterpret_cast<uint4*>(&w2bT[(size_t)n * HIDDEN + k0]) =
        *reinterpret_cast<const uint4*>(o);
  } else if (t < 53248) {                // codebook 3-way bf16 split, 8 elems/thread
    const int e0 = (t - 20480) * 8;
    alignas(16) unsigned short oh[8], om[8], ol[8];
#pragma unroll
    for (int q = 0; q < 8; ++q) split3(cbk[e0 + q], oh[q], om[q], ol[q]);
    *reinterpret_cast<uint4*>(&cbh[e0]) = *reinterpret_cast<const uint4*>(oh);
    *reinterpret_cast<uint4*>(&cbm[e0]) = *reinterpret_cast<const uint4*>(om);
    *reinterpret_cast<uint4*>(&cbl[e0]) = *reinterpret_cast<const uint4*>(ol);
  }
}

// ---------------------------------------------------------------------------
// vq_mfma: VQ nearest-codebook search on the MATRIX pipe.
//
// cross via 3-way bf16 split (6 MFMAs/acc: hh,hm,mh,hl,mm,lh) -> fp32-class
// error; score = -0.5*||c||^2 + cross (seeded via C-in); argMAX score.
//
// v3 (round-2 LDS staging REVERTED -- unproven race; this is the proven
// round-1 global-load datapath, bit-identical scores):
//  * __launch_bounds__(256, 4): round-1's VGPR_Count=44 shows the compiler
//    targeted 8 waves/SIMD and serialized ~100 loads/2-chunks with full L2
//    latency each (the 108us). Grid only supports ~4 waves/SIMD anyway ->
//    allow ~128 VGPRs so loads can stay in flight.
//  * Chunk-batched fragment loads: all 16 loads (4 ntiles x {bh,bm,bl,cn})
//    hoisted above the chunk's 48 MFMAs -> one vmcnt window per chunk,
//    covered by ~290cy of MFMA issue + 4-way TLP.
//
// Block: 256 thr = 4 waves x 32 rows = 128 rows; grid (125, 8 groups).
// ---------------------------------------------------------------------------
__global__ __launch_bounds__(256, 4) void vq_mfma(
    const float* __restrict__ z_e, const float* __restrict__ cb,
    const float* __restrict__ cnh,           // = -0.5*||c||^2
    const unsigned short* __restrict__ cbh,
    const unsigned short* __restrict__ cbm,
    const unsigned short* __restrict__ cbl,
    float* __restrict__ z_q, unsigned short* __restrict__ zqb,
    float* __restrict__ idx_out, float* __restrict__ loss_acc) {
  const int g    = blockIdx.y;
  const int row0 = blockIdx.x * 128;
  const int tid  = threadIdx.x;
  const int wave = tid >> 6;
  const int lane = tid & 63;
  const int quad = lane >> 4;
  const int l16  = lane & 15;

  // ---- A fragments: rows wave*32 + mt*16 + l16, dims quad*8..+8 (in-reg split)
  bf16x8 ah[2], am[2], al[2];
#pragma unroll
  for (int mt = 0; mt < 2; ++mt) {
    const float* zp = &z_e[(size_t)(row0 + wave * 32 + mt * 16 + l16) * LATENT
                           + g * GD + quad * 8];
    const float4 x0 = *reinterpret_cast<const float4*>(zp);
    const float4 x1 = *reinterpret_cast<const float4*>(zp + 4);
    const float xv[8] = {x0.x, x0.y, x0.z, x0.w, x1.x, x1.y, x1.z, x1.w};
    bf16x8 vh, vm, vl;
#pragma unroll
    for (int j = 0; j < 8; ++j) {
      unsigned short sh, sm, sl;
      split3(xv[j], sh, sm, sl);
      vh[j] = (short)sh; vm[j] = (short)sm; vl[j] = (short)sl;
    }
    ah[mt] = vh; am[mt] = vm; al[mt] = vl;
  }

  const size_t cb0 = (size_t)g * KQ * GD;
  const float* cng = cnh + g * KQ;

  float best[8];
  int   bidx[8];
#pragma unroll
  for (int i = 0; i < 8; ++i) { best[i] = -3.0e38f; bidx[i] = 0; }

#pragma unroll 2
  for (int ch = 0; ch < 16; ++ch) {
    // ---- batched loads for the whole chunk (issued before any MFMA)
    bf16x8 Fh[4], Fm[4], Fl[4];
    float  Fc[4];
#pragma unroll
    for (int nt = 0; nt < 4; ++nt) {
      const int code = ch * 64 + nt * 16 + l16;          // per-lane, ascending
      const size_t cba = cb0 + (size_t)code * GD + quad * 8;
      Fh[nt] = *reinterpret_cast<const bf16x8*>(&cbh[cba]);
      Fm[nt] = *reinterpret_cast<const bf16x8*>(&cbm[cba]);
      Fl[nt] = *reinterpret_cast<const bf16x8*>(&cbl[cba]);
      Fc[nt] = cng[code];
    }
    // ---- 48 MFMAs + selects (order per-acc identical to round 1 -> bits)
#pragma unroll
    for (int nt = 0; nt < 4; ++nt) {
      const float c0 = Fc[nt];
      f32x4 a0 = {c0, c0, c0, c0};                       // seed with -0.5||c||^2
      f32x4 a1 = a0;
      a0 = __builtin_amdgcn_mfma_f32_16x16x32_bf16(ah[0], Fh[nt], a0, 0, 0, 0);
      a1 = __builtin_amdgcn_mfma_f32_16x16x32_bf16(ah[1], Fh[nt], a1, 0, 0, 0);
      a0 = __builtin_amdgcn_mfma_f32_16x16x32_bf16(ah[0], Fm[nt], a0, 0, 0, 0);
      a1 = __builtin_amdgcn_mfma_f32_16x16x32_bf16(ah[1], Fm[nt], a1, 0, 0, 0);
      a0 = __builtin_amdgcn_mfma_f32_16x16x32_bf16(am[0], Fh[nt], a0, 0, 0, 0);
      a1 = __builtin_amdgcn_mfma_f32_16x16x32_bf16(am[1], Fh[nt], a1, 0, 0, 0);
      a0 = __builtin_amdgcn_mfma_f32_16x16x32_bf16(ah[0], Fl[nt], a0, 0, 0, 0);
      a1 = __builtin_amdgcn_mfma_f32_16x16x32_bf16(ah[1], Fl[nt], a1, 0, 0, 0);
      a0 = __builtin_amdgcn_mfma_f32_16x16x32_bf16(am[0], Fm[nt], a0, 0, 0, 0);
      a1 = __builtin_amdgcn_mfma_f32_16x16x32_bf16(am[1], Fm[nt], a1, 0, 0, 0);
      a0 = __builtin_amdgcn_mfma_f32_16x16x32_bf16(al[0], Fh[nt], a0, 0, 0, 0);
      a1 = __builtin_amdgcn_mfma_f32_16x16x32_bf16(al[1], Fh[nt], a1, 0, 0, 0);
      const int code = ch * 64 + nt * 16 + l16;
      // argmax update; strict > keeps first (lowest) code on exact ties
#pragma unroll
      for (int r = 0; r < 4; ++r) {
        if (a0[r] > best[r])     { best[r] = a0[r];     bidx[r] = code; }
        if (a1[r] > best[4 + r]) { best[4 + r] = a1[r]; bidx[4 + r] = code; }
      }
    }
  }

  // ---- per-row reduce across the 16 l16-lanes (codes == l16 mod 16), then
  // 16 lanes cooperate on the 32-dim epilogue (2 dims each).
  float sse_local = 0.0f;
#pragma unroll
  for (int s8 = 0; s8 < 8; ++s8) {
    float mb = best[s8];
    int   mi = bidx[s8];
#pragma unroll
    for (int m = 1; m < 16; m <<= 1) {
      const float ov = __shfl_xor(mb, m, 64);
      const int   oi = __shfl_xor(mi, m, 64);
      if (ov > mb || (ov == mb && oi < mi)) { mb = ov; mi = oi; }
    }
    // all 16 lanes of this quad-group now agree on (mb, mi)
    const int mt  = s8 >> 2;
    const int r   = s8 & 3;
    const int row = row0 + wave * 32 + mt * 16 + quad * 4 + r;
    const float2 cw = *reinterpret_cast<const float2*>(
        &cb[cb0 + (size_t)mi * GD + 2 * l16]);
    const float2 zv = *reinterpret_cast<const float2*>(
        &z_e[(size_t)row * LATENT + g * GD + 2 * l16]);
    const float d0 = cw.x - zv.x;
    const float d1 = cw.y - zv.y;
    sse_local = fmaf(d0, d0, fmaf(d1, d1, sse_local));
    *reinterpret_cast<float2*>(
        &z_q[(size_t)row * LATENT + g * GD + 2 * l16]) = cw;
    const unsigned pz = (unsigned)f2bf(cw.x) | ((unsigned)f2bf(cw.y) << 16);
    *reinterpret_cast<unsigned*>(
        &zqb[(size_t)row * LATENT + g * GD + 2 * l16]) = pz;
    if (l16 == 0) idx_out[(size_t)row * GQ + g] = (float)mi;
  }

#pragma unroll
  for (int m = 1; m < 64; m <<= 1) sse_local += __shfl_xor(sse_local, m, 64);
  if (lane == 0) atomicAdd(loss_acc, sse_local);
}

// ---------------------------------------------------------------------------
extern "C" void kernel_launch(void* const* d_in, const int* in_sizes, int n_in,
                              void* d_out, int out_size, void* d_ws, size_t ws_size,
                              hipStream_t stream) {
  const float* bands  = (const float*)d_in[0];
  const float* enc_w1 = (const float*)d_in[1];
  const float* enc_b1 = (const float*)d_in[2];
  const float* enc_w2 = (const float*)d_in[3];
  const float* enc_b2 = (const float*)d_in[4];
  const float* cbooks = (const float*)d_in[5];
  const float* dec_w1 = (const float*)d_in[6];
  const float* dec_b1 = (const float*)d_in[7];
  const float* dec_w2 = (const float*)d_in[8];
  const float* dec_b2 = (const float*)d_in[9];

  float* out = (float*)d_out;
  float* ws  = (float*)d_ws;

  float* bands_hat = out + OUT_BH;
  float* z_e       = out + OUT_ZE;
  float* z_q       = out + OUT_ZQ;
  float* idx_f     = out + OUT_IDX;
  float* loss_out  = out + OUT_LOSS;

  float* H        = ws + WS_H;
  float* cn       = ws + WS_CN;
  float* loss_acc = ws + WS_LOSS;
  unsigned short* h2bf = (unsigned short*)(ws + WS_H2BF_F);
  unsigned short* zqb  = (unsigned short*)(ws + WS_ZQB_F);
  unsigned short* w1bT = (unsigned short*)(ws + WS_W1B_F);
  unsigned short* w2bT = (unsigned short*)(ws + WS_W2B_F);
  unsigned short* cbh  = (unsigned short*)(ws + WS_CBH_F);
  unsigned short* cbm  = (unsigned short*)(ws + WS_CBM_F);
  unsigned short* cbl  = (unsigned short*)(ws + WS_CBL_F);

  // cn (= -0.5||c||^2) + loss zero (safe: outside H region)
  prep_cn<<<dim3(32), dim3(256), 0, stream>>>(cbooks, cn, loss_acc);

  // Encoder (fp32): H = relu(bands@W1+b1); z_e = H@W2+b2 (enc2 BK=32)
  gemm_f32<128, 8, 8, 16, true ><<<dim3(HIDDEN / 128, NROWS / 128), dim3(256), 0, stream>>>(
      bands, enc_w1, enc_b1, H, NROWS, HIDDEN, NBANDS);
  gemm_f32<64, 4, 8, 32, false><<<dim3(LATENT / 64, NROWS / 128), dim3(256), 0, stream>>>(
      H, enc_w2, enc_b2, z_e, NROWS, LATENT, HIDDEN);

  // Decoder weights -> transposed bf16; codebook -> 3-way bf16 split
  // (H is dead now; overlays are safe)
  prep_wT<<<dim3(208), dim3(256), 0, stream>>>(
      dec_w1, dec_w2, cbooks, w1bT, w2bT, cbh, cbm, cbl);

  // VQ on the matrix pipe (fp32-class accuracy via 6-MFMA split)
  vq_mfma<<<dim3(NROWS / 128, GQ), dim3(256), 0, stream>>>(
      z_e, cbooks, cn, cbh, cbm, cbl, z_q, zqb, idx_f, loss_acc);

  // Decoder (bf16 MFMA, transposed-weight staging); dec1 finalizes loss
  gemm_bf16_mfma<32, true, true ><<<dim3(HIDDEN / 64, NROWS / 128), dim3(256), 0, stream>>>(
      zqb, w1bT, dec_b1, (void*)h2bf, NROWS, HIDDEN, LATENT, loss_acc, loss_out);
  gemm_bf16_mfma<16, false, false><<<dim3(NBANDS / 64, NROWS / 64), dim3(256), 0, stream>>>(
      h2bf, w2bT, dec_b2, (void*)bands_hat, NROWS, NBANDS, HIDDEN, loss_acc, loss_out);
}

// Round 4
// 288.826 us; speedup vs baseline: 1.1370x; 1.0180x over previous
//
#include <hip/hip_runtime.h>

// Problem constants
#define NBANDS 64
#define LATENT 256
#define HIDDEN 512
#define GQ 8
#define KQ 1024
#define GD 32
#define NROWS 16000   // B*T = 16*1000

// d_out float offsets
#define OUT_BH   0
#define OUT_ZE   1024000
#define OUT_ZQ   5120000
#define OUT_IDX  9216000
#define OUT_LOSS 9344000

// ws float offsets.  H region [0,8192000) is live ONLY between enc1 and enc2;
// bf16 buffers overlay it and MUST be written after enc2.
#define WS_H     0
#define WS_H2BF_F  0
#define WS_ZQB_F   4096000
#define WS_W1B_F   6144000
#define WS_W2B_F   6209536
// 3-way bf16 split of codebooks (written by prep_wT, read by vq_mfma).
// 262144 ushort = 131072 floats each; all inside dead-H overlay region.
#define WS_CBH_F   6240000
#define WS_CBM_F   6400000
#define WS_CBL_F   6560000
#define WS_CN    8192000
#define WS_LOSS  8200192

typedef __attribute__((ext_vector_type(8))) short bf16x8;
typedef __attribute__((ext_vector_type(4))) float f32x4;

__device__ __forceinline__ unsigned short f2bf(float f) {
  unsigned u = __builtin_bit_cast(unsigned, f);
  unsigned r = u + 0x7FFFu + ((u >> 16) & 1u);   // RNE; inputs finite
  return (unsigned short)(r >> 16);
}

__device__ __forceinline__ float bf2f(unsigned short h) {
  return __builtin_bit_cast(float, ((unsigned)h) << 16);
}

// 3-way bf16 split: x ~= h + m + l with residual ~2^-24 |x|.
__device__ __forceinline__ void split3(float x, unsigned short& h,
                                       unsigned short& m, unsigned short& l) {
  h = f2bf(x);
  const float r1 = x - bf2f(h);
  m = f2bf(r1);
  const float r2 = r1 - bf2f(m);
  l = f2bf(r2);
}

// ---------------------------------------------------------------------------
// fp32 GEMM, 128xBN tile, TMxTN microtile, templated BK, 256 threads.
// Ascending-k accumulation regardless of BK -> bit-identical results.
// ---------------------------------------------------------------------------
template<int BN, int TM, int TN, int BK, bool RELU>
__global__ __launch_bounds__(256) void gemm_f32(
    const float* __restrict__ A, const float* __restrict__ B,
    const float* __restrict__ bias, float* __restrict__ C,
    int M, int N, int K) {
  constexpr int BM = 128;
  constexpr int NTX = BN / TN;
  constexpr int AF4 = BK / 8;
  constexpr int QPR = BN / 4;
  constexpr int BF4 = BK * BN / 1024;

  __shared__ float As[BK][BM + 8];
  __shared__ float Bs[BK][BN + 4];

  const int tid = threadIdx.x;
  const int tx = tid % NTX;
  const int ty = tid / NTX;
  const int row0 = blockIdx.y * BM;
  const int col0 = blockIdx.x * BN;

  const int arow = tid >> 1;
  const int akq  = (tid & 1) * (BK / 2);

  float acc[TM][TN] = {};

  for (int k0 = 0; k0 < K; k0 += BK) {
    float4 av[AF4], bv[BF4];
#pragma unroll
    for (int q = 0; q < AF4; ++q)
      av[q] = *reinterpret_cast<const float4*>(
          &A[(size_t)(row0 + arow) * K + k0 + akq + q * 4]);
#pragma unroll
    for (int t = 0; t < BF4; ++t) {
      const int qq = tid * BF4 + t;
      const int bk = qq / QPR, bn4 = qq % QPR;
      bv[t] = *reinterpret_cast<const float4*>(
          &B[(size_t)(k0 + bk) * N + col0 + bn4 * 4]);
    }
    __syncthreads();
#pragma unroll
    for (int q = 0; q < AF4; ++q) {
      As[akq + q * 4 + 0][arow] = av[q].x;
      As[akq + q * 4 + 1][arow] = av[q].y;
      As[akq + q * 4 + 2][arow] = av[q].z;
      As[akq + q * 4 + 3][arow] = av[q].w;
    }
#pragma unroll
    for (int t = 0; t < BF4; ++t) {
      const int qq = tid * BF4 + t;
      const int bk = qq / QPR, bn4 = qq % QPR;
      *reinterpret_cast<float4*>(&Bs[bk][bn4 * 4]) = bv[t];
    }
    __syncthreads();

#pragma unroll
    for (int kk = 0; kk < BK; ++kk) {
      float a[TM], b[TN];
#pragma unroll
      for (int q = 0; q < TM / 4; ++q) {
        float4 v = *reinterpret_cast<const float4*>(&As[kk][ty * TM + q * 4]);
        a[q * 4 + 0] = v.x; a[q * 4 + 1] = v.y;
        a[q * 4 + 2] = v.z; a[q * 4 + 3] = v.w;
      }
#pragma unroll
      for (int q = 0; q < TN / 4; ++q) {
        float4 v = *reinterpret_cast<const float4*>(&Bs[kk][tx * TN + q * 4]);
        b[q * 4 + 0] = v.x; b[q * 4 + 1] = v.y;
        b[q * 4 + 2] = v.z; b[q * 4 + 3] = v.w;
      }
#pragma unroll
      for (int i = 0; i < TM; ++i)
#pragma unroll
        for (int j = 0; j < TN; ++j)
          acc[i][j] = fmaf(a[i], b[j], acc[i][j]);
    }
  }

  float bb[TN];
#pragma unroll
  for (int q = 0; q < TN / 4; ++q) {
    float4 v = *reinterpret_cast<const float4*>(&bias[col0 + tx * TN + q * 4]);
    bb[q * 4 + 0] = v.x; bb[q * 4 + 1] = v.y;
    bb[q * 4 + 2] = v.z; bb[q * 4 + 3] = v.w;
  }
#pragma unroll
  for (int i = 0; i < TM; ++i) {
    const int r = row0 + ty * TM + i;
#pragma unroll
    for (int q = 0; q < TN / 4; ++q) {
      float4 v;
      float* vp = &v.x;
#pragma unroll
      for (int j = 0; j < 4; ++j) {
        float t = acc[i][q * 4 + j] + bb[q * 4 + j];
        if (RELU) t = fmaxf(t, 0.0f);
        vp[j] = t;
      }
      *reinterpret_cast<float4*>(&C[(size_t)r * N + col0 + tx * TN + q * 4]) = v;
    }
  }
}

// ---------------------------------------------------------------------------
// bf16 MFMA GEMM with TRANSPOSED B (BT[n][k]) -> b128 B-staging.
// DO_LOSS: block(0,0) tid0 finalizes the vq loss scalar.
// ---------------------------------------------------------------------------
template<int WM, bool OUT_BF16, bool DO_LOSS>
__global__ __launch_bounds__(256) void gemm_bf16_mfma(
    const unsigned short* __restrict__ A, const unsigned short* __restrict__ BT,
    const float* __restrict__ bias, void* __restrict__ Cout,
    int M, int N, int K,
    const float* __restrict__ loss_acc, float* __restrict__ loss_out) {
  constexpr int BM = 4 * WM;
  constexpr int MT = WM / 16;

  __shared__ unsigned short As[BM][40];
  __shared__ unsigned short Bs[64][40];

  const int tid  = threadIdx.x;
  const int wave = tid >> 6;
  const int lane = tid & 63;
  const int quad = lane >> 4;
  const int l16  = lane & 15;
  const int row0 = blockIdx.y * BM;
  const int col0 = blockIdx.x * 64;

  if (DO_LOSS && blockIdx.x == 0 && blockIdx.y == 0 && tid == 0)
    loss_out[0] = 0.5f * loss_acc[0] / (float)((size_t)NROWS * GD);

  f32x4 acc[MT][4];
#pragma unroll
  for (int mt = 0; mt < MT; ++mt)
#pragma unroll
    for (int nt = 0; nt < 4; ++nt) acc[mt][nt] = (f32x4){0.f, 0.f, 0.f, 0.f};

  for (int k0 = 0; k0 < K; k0 += 32) {
    __syncthreads();
    if constexpr (BM == 128) {
      const int r = tid >> 1, seg = (tid & 1) * 16;
      const uint4* src = reinterpret_cast<const uint4*>(
          &A[(size_t)(row0 + r) * K + k0 + seg]);
      uint4* dst = reinterpret_cast<uint4*>(&As[r][seg]);
      dst[0] = src[0]; dst[1] = src[1];
    } else {
      const int r = tid >> 2, seg = (tid & 3) * 8;
      *reinterpret_cast<uint4*>(&As[r][seg]) =
          *reinterpret_cast<const uint4*>(&A[(size_t)(row0 + r) * K + k0 + seg]);
    }
    {
      const int n = tid >> 2, kc = (tid & 3) * 8;
      *reinterpret_cast<uint4*>(&Bs[n][kc]) =
          *reinterpret_cast<const uint4*>(&BT[(size_t)(col0 + n) * K + k0 + kc]);
    }
    __syncthreads();

    bf16x8 af[MT], bf[4];
#pragma unroll
    for (int mt = 0; mt < MT; ++mt)
      af[mt] = *reinterpret_cast<const bf16x8*>(
          &As[wave * WM + mt * 16 + l16][quad * 8]);
#pragma unroll
    for (int nt = 0; nt < 4; ++nt)
      bf[nt] = *reinterpret_cast<const bf16x8*>(&Bs[nt * 16 + l16][quad * 8]);
#pragma unroll
    for (int mt = 0; mt < MT; ++mt)
#pragma unroll
      for (int nt = 0; nt < 4; ++nt)
        acc[mt][nt] = __builtin_amdgcn_mfma_f32_16x16x32_bf16(
            af[mt], bf[nt], acc[mt][nt], 0, 0, 0);
  }

#pragma unroll
  for (int mt = 0; mt < MT; ++mt)
#pragma unroll
    for (int nt = 0; nt < 4; ++nt) {
      const int col = col0 + nt * 16 + l16;
      const float bv = bias[col];
#pragma unroll
      for (int r = 0; r < 4; ++r) {
        const int grow = row0 + wave * WM + mt * 16 + quad * 4 + r;
        float v = acc[mt][nt][r] + bv;
        if constexpr (OUT_BF16) {
          v = fmaxf(v, 0.0f);
          ((unsigned short*)Cout)[(size_t)grow * N + col] = f2bf(v);
        } else {
          ((float*)Cout)[(size_t)grow * N + col] = v;
        }
      }
    }
}

// ---------------------------------------------------------------------------
// prep_cn: cn = -0.5*||codebook||^2 (MFMA-accumulator seed for argmax form)
// + zero loss accumulator.  Runs FIRST.
// ---------------------------------------------------------------------------
__global__ void prep_cn(const float* __restrict__ cb, float* __restrict__ cn,
                        float* __restrict__ loss_acc) {
  const int i = blockIdx.x * 256 + threadIdx.x;
  if (i == 0) loss_acc[0] = 0.0f;
  if (i < GQ * KQ) {
    const float* c = cb + (size_t)i * GD;
    float s = 0.0f;
#pragma unroll
    for (int d = 0; d < GD; ++d) s = fmaf(c[d], c[d], s);
    cn[i] = -0.5f * s;
  }
}

// ---------------------------------------------------------------------------
// prep_wT: decoder weights -> TRANSPOSED bf16 (w1bT, w2bT)
// + codebook -> 3-way bf16 split (cbh/cbm/cbl) for the fp32-accurate VQ MFMA.
// MUST run after enc2 (all outputs overlay the then-dead fp32 H region).
// ---------------------------------------------------------------------------
__global__ void prep_wT(const float* __restrict__ w1, const float* __restrict__ w2,
                        const float* __restrict__ cbk,
                        unsigned short* __restrict__ w1bT,
                        unsigned short* __restrict__ w2bT,
                        unsigned short* __restrict__ cbh,
                        unsigned short* __restrict__ cbm,
                        unsigned short* __restrict__ cbl) {
  const int t = blockIdx.x * 256 + threadIdx.x;
  if (t < 16384) {                       // w1: [256 k][512 n] -> w1bT[n][k]
    const int n = t >> 5, k0 = (t & 31) * 8;
    alignas(16) unsigned short o[8];
#pragma unroll
    for (int q = 0; q < 8; ++q) o[q] = f2bf(w1[(size_t)(k0 + q) * HIDDEN + n]);
    *reinterpret_cast<uint4*>(&w1bT[(size_t)n * LATENT + k0]) =
        *reinterpret_cast<const uint4*>(o);
  } else if (t < 20480) {                // w2: [512 k][64 n] -> w2bT[n][k]
    const int u = t - 16384;
    const int n = u >> 6, k0 = (u & 63) * 8;
    alignas(16) unsigned short o[8];
#pragma unroll
    for (int q = 0; q < 8; ++q) o[q] = f2bf(w2[(size_t)(k0 + q) * NBANDS + n]);
    *reinterpret_cast<uint4*>(&w2bT[(size_t)n * HIDDEN + k0]) =
        *reinterpret_cast<const uint4*>(o);
  } else if (t < 53248) {                // codebook 3-way bf16 split, 8 elems/thread
    const int e0 = (t - 20480) * 8;
    alignas(16) unsigned short oh[8], om[8], ol[8];
#pragma unroll
    for (int q = 0; q < 8; ++q) split3(cbk[e0 + q], oh[q], om[q], ol[q]);
    *reinterpret_cast<uint4*>(&cbh[e0]) = *reinterpret_cast<const uint4*>(oh);
    *reinterpret_cast<uint4*>(&cbm[e0]) = *reinterpret_cast<const uint4*>(om);
    *reinterpret_cast<uint4*>(&cbl[e0]) = *reinterpret_cast<const uint4*>(ol);
  }
}

// ---------------------------------------------------------------------------
// vq_mfma v4: VQ nearest-codebook search on the MATRIX pipe.
//
// cross via 3-way bf16 split (6 MFMAs/acc: hh,hm,mh,hl,mm,lh) -> fp32-class
// error; score = -0.5*||c||^2 + cross (seeded via C-in); argMAX score.
//
// Round-3 diagnosis: VGPR=64 -> chunk batch couldn't live in registers ->
// per-nt serialization: vmcnt wait + 6-deep dependent MFMA chain at ILP=2
// (dep latency ~25-30cy) -> matrix pipe ~75% idle (MfmaUtil 20%).
// v4 fixes the ILP, not the occupancy:
//  * __launch_bounds__(256, 2): up to 256 VGPR (grid only sustains ~2
//    blocks/CU anyway; ILP > TLP here).
//  * Tier-interleaved schedule: all 12 b128 + 4 cn loads of a chunk first,
//    then 48 MFMAs issued tier-by-tier ACROSS all 8 accumulators -> 8
//    independent MFMAs between dependent pairs -> chain latency hidden.
//  * Explicit 2-chunk X/Y register pipeline: loads of chunk c+1 issue
//    before compute of chunk c -> one vmcnt window under 48 MFMAs.
// Per-accumulator MFMA order and select order are UNCHANGED -> bit-identical.
//
// Block: 256 thr = 4 waves x 32 rows = 128 rows; grid (125, 8 groups).
// ---------------------------------------------------------------------------
__device__ __forceinline__ void vq_load(
    const unsigned short* __restrict__ cbh,
    const unsigned short* __restrict__ cbm,
    const unsigned short* __restrict__ cbl,
    const float* __restrict__ cng, size_t cb0, int ch, int l16, int quad,
    bf16x8 (&Fh)[4], bf16x8 (&Fm)[4], bf16x8 (&Fl)[4], float (&Fc)[4]) {
#pragma unroll
  for (int nt = 0; nt < 4; ++nt) {
    const int code = ch * 64 + nt * 16 + l16;
    const size_t cba = cb0 + (size_t)code * GD + quad * 8;
    Fh[nt] = *reinterpret_cast<const bf16x8*>(&cbh[cba]);
    Fm[nt] = *reinterpret_cast<const bf16x8*>(&cbm[cba]);
    Fl[nt] = *reinterpret_cast<const bf16x8*>(&cbl[cba]);
    Fc[nt] = cng[code];
  }
}

__device__ __forceinline__ void vq_compute(
    const bf16x8 (&ah)[2], const bf16x8 (&am)[2], const bf16x8 (&al)[2],
    const bf16x8 (&Fh)[4], const bf16x8 (&Fm)[4], const bf16x8 (&Fl)[4],
    const float (&Fc)[4], int ch, int l16,
    float (&best)[8], int (&bidx)[8]) {
  f32x4 acc[8];
#pragma unroll
  for (int nt = 0; nt < 4; ++nt) {
    acc[2 * nt]     = (f32x4){Fc[nt], Fc[nt], Fc[nt], Fc[nt]};
    acc[2 * nt + 1] = acc[2 * nt];
  }
  // Tier order per accumulator: ah*h, ah*m, am*h, ah*l, am*m, al*h
  // (identical to rounds 1/3); interleaved across 8 accs for ILP=8.
#pragma unroll
  for (int nt = 0; nt < 4; ++nt) {
    acc[2*nt]   = __builtin_amdgcn_mfma_f32_16x16x32_bf16(ah[0], Fh[nt], acc[2*nt],   0, 0, 0);
    acc[2*nt+1] = __builtin_amdgcn_mfma_f32_16x16x32_bf16(ah[1], Fh[nt], acc[2*nt+1], 0, 0, 0);
  }
#pragma unroll
  for (int nt = 0; nt < 4; ++nt) {
    acc[2*nt]   = __builtin_amdgcn_mfma_f32_16x16x32_bf16(ah[0], Fm[nt], acc[2*nt],   0, 0, 0);
    acc[2*nt+1] = __builtin_amdgcn_mfma_f32_16x16x32_bf16(ah[1], Fm[nt], acc[2*nt+1], 0, 0, 0);
  }
#pragma unroll
  for (int nt = 0; nt < 4; ++nt) {
    acc[2*nt]   = __builtin_amdgcn_mfma_f32_16x16x32_bf16(am[0], Fh[nt], acc[2*nt],   0, 0, 0);
    acc[2*nt+1] = __builtin_amdgcn_mfma_f32_16x16x32_bf16(am[1], Fh[nt], acc[2*nt+1], 0, 0, 0);
  }
#pragma unroll
  for (int nt = 0; nt < 4; ++nt) {
    acc[2*nt]   = __builtin_amdgcn_mfma_f32_16x16x32_bf16(ah[0], Fl[nt], acc[2*nt],   0, 0, 0);
    acc[2*nt+1] = __builtin_amdgcn_mfma_f32_16x16x32_bf16(ah[1], Fl[nt], acc[2*nt+1], 0, 0, 0);
  }
#pragma unroll
  for (int nt = 0; nt < 4; ++nt) {
    acc[2*nt]   = __builtin_amdgcn_mfma_f32_16x16x32_bf16(am[0], Fm[nt], acc[2*nt],   0, 0, 0);
    acc[2*nt+1] = __builtin_amdgcn_mfma_f32_16x16x32_bf16(am[1], Fm[nt], acc[2*nt+1], 0, 0, 0);
  }
#pragma unroll
  for (int nt = 0; nt < 4; ++nt) {
    acc[2*nt]   = __builtin_amdgcn_mfma_f32_16x16x32_bf16(al[0], Fh[nt], acc[2*nt],   0, 0, 0);
    acc[2*nt+1] = __builtin_amdgcn_mfma_f32_16x16x32_bf16(al[1], Fh[nt], acc[2*nt+1], 0, 0, 0);
  }
  // argmax update; nt ascending -> same compare order as before (tie-break ok)
#pragma unroll
  for (int nt = 0; nt < 4; ++nt) {
    const int code = ch * 64 + nt * 16 + l16;
#pragma unroll
    for (int r = 0; r < 4; ++r) {
      if (acc[2*nt][r]   > best[r])     { best[r]     = acc[2*nt][r];   bidx[r]     = code; }
      if (acc[2*nt+1][r] > best[4 + r]) { best[4 + r] = acc[2*nt+1][r]; bidx[4 + r] = code; }
    }
  }
}

__global__ __launch_bounds__(256, 2) void vq_mfma(
    const float* __restrict__ z_e, const float* __restrict__ cb,
    const float* __restrict__ cnh,           // = -0.5*||c||^2
    const unsigned short* __restrict__ cbh,
    const unsigned short* __restrict__ cbm,
    const unsigned short* __restrict__ cbl,
    float* __restrict__ z_q, unsigned short* __restrict__ zqb,
    float* __restrict__ idx_out, float* __restrict__ loss_acc) {
  const int g    = blockIdx.y;
  const int row0 = blockIdx.x * 128;
  const int tid  = threadIdx.x;
  const int wave = tid >> 6;
  const int lane = tid & 63;
  const int quad = lane >> 4;
  const int l16  = lane & 15;

  // ---- A fragments: rows wave*32 + mt*16 + l16, dims quad*8..+8 (in-reg split)
  bf16x8 ah[2], am[2], al[2];
#pragma unroll
  for (int mt = 0; mt < 2; ++mt) {
    const float* zp = &z_e[(size_t)(row0 + wave * 32 + mt * 16 + l16) * LATENT
                           + g * GD + quad * 8];
    const float4 x0 = *reinterpret_cast<const float4*>(zp);
    const float4 x1 = *reinterpret_cast<const float4*>(zp + 4);
    const float xv[8] = {x0.x, x0.y, x0.z, x0.w, x1.x, x1.y, x1.z, x1.w};
    bf16x8 vh, vm, vl;
#pragma unroll
    for (int j = 0; j < 8; ++j) {
      unsigned short sh, sm, sl;
      split3(xv[j], sh, sm, sl);
      vh[j] = (short)sh; vm[j] = (short)sm; vl[j] = (short)sl;
    }
    ah[mt] = vh; am[mt] = vm; al[mt] = vl;
  }

  const size_t cb0 = (size_t)g * KQ * GD;
  const float* cng = cnh + g * KQ;

  float best[8];
  int   bidx[8];
#pragma unroll
  for (int i = 0; i < 8; ++i) { best[i] = -3.0e38f; bidx[i] = 0; }

  // ---- 2-chunk X/Y software pipeline over 16 chunks
  bf16x8 Xh[4], Xm[4], Xl[4]; float Xc[4];
  bf16x8 Yh[4], Ym[4], Yl[4]; float Yc[4];
  vq_load(cbh, cbm, cbl, cng, cb0, 0, l16, quad, Xh, Xm, Xl, Xc);
#pragma unroll 1
  for (int cp = 0; cp < 8; ++cp) {
    vq_load(cbh, cbm, cbl, cng, cb0, 2 * cp + 1, l16, quad, Yh, Ym, Yl, Yc);
    vq_compute(ah, am, al, Xh, Xm, Xl, Xc, 2 * cp, l16, best, bidx);
    if (cp < 7)
      vq_load(cbh, cbm, cbl, cng, cb0, 2 * cp + 2, l16, quad, Xh, Xm, Xl, Xc);
    vq_compute(ah, am, al, Yh, Ym, Yl, Yc, 2 * cp + 1, l16, best, bidx);
  }

  // ---- per-row reduce across the 16 l16-lanes (codes == l16 mod 16), then
  // 16 lanes cooperate on the 32-dim epilogue (2 dims each).
  float sse_local = 0.0f;
#pragma unroll
  for (int s8 = 0; s8 < 8; ++s8) {
    float mb = best[s8];
    int   mi = bidx[s8];
#pragma unroll
    for (int m = 1; m < 16; m <<= 1) {
      const float ov = __shfl_xor(mb, m, 64);
      const int   oi = __shfl_xor(mi, m, 64);
      if (ov > mb || (ov == mb && oi < mi)) { mb = ov; mi = oi; }
    }
    // all 16 lanes of this quad-group now agree on (mb, mi)
    const int mt  = s8 >> 2;
    const int r   = s8 & 3;
    const int row = row0 + wave * 32 + mt * 16 + quad * 4 + r;
    const float2 cw = *reinterpret_cast<const float2*>(
        &cb[cb0 + (size_t)mi * GD + 2 * l16]);
    const float2 zv = *reinterpret_cast<const float2*>(
        &z_e[(size_t)row * LATENT + g * GD + 2 * l16]);
    const float d0 = cw.x - zv.x;
    const float d1 = cw.y - zv.y;
    sse_local = fmaf(d0, d0, fmaf(d1, d1, sse_local));
    *reinterpret_cast<float2*>(
        &z_q[(size_t)row * LATENT + g * GD + 2 * l16]) = cw;
    const unsigned pz = (unsigned)f2bf(cw.x) | ((unsigned)f2bf(cw.y) << 16);
    *reinterpret_cast<unsigned*>(
        &zqb[(size_t)row * LATENT + g * GD + 2 * l16]) = pz;
    if (l16 == 0) idx_out[(size_t)row * GQ + g] = (float)mi;
  }

#pragma unroll
  for (int m = 1; m < 64; m <<= 1) sse_local += __shfl_xor(sse_local, m, 64);
  if (lane == 0) atomicAdd(loss_acc, sse_local);
}

// ---------------------------------------------------------------------------
extern "C" void kernel_launch(void* const* d_in, const int* in_sizes, int n_in,
                              void* d_out, int out_size, void* d_ws, size_t ws_size,
                              hipStream_t stream) {
  const float* bands  = (const float*)d_in[0];
  const float* enc_w1 = (const float*)d_in[1];
  const float* enc_b1 = (const float*)d_in[2];
  const float* enc_w2 = (const float*)d_in[3];
  const float* enc_b2 = (const float*)d_in[4];
  const float* cbooks = (const float*)d_in[5];
  const float* dec_w1 = (const float*)d_in[6];
  const float* dec_b1 = (const float*)d_in[7];
  const float* dec_w2 = (const float*)d_in[8];
  const float* dec_b2 = (const float*)d_in[9];

  float* out = (float*)d_out;
  float* ws  = (float*)d_ws;

  float* bands_hat = out + OUT_BH;
  float* z_e       = out + OUT_ZE;
  float* z_q       = out + OUT_ZQ;
  float* idx_f     = out + OUT_IDX;
  float* loss_out  = out + OUT_LOSS;

  float* H        = ws + WS_H;
  float* cn       = ws + WS_CN;
  float* loss_acc = ws + WS_LOSS;
  unsigned short* h2bf = (unsigned short*)(ws + WS_H2BF_F);
  unsigned short* zqb  = (unsigned short*)(ws + WS_ZQB_F);
  unsigned short* w1bT = (unsigned short*)(ws + WS_W1B_F);
  unsigned short* w2bT = (unsigned short*)(ws + WS_W2B_F);
  unsigned short* cbh  = (unsigned short*)(ws + WS_CBH_F);
  unsigned short* cbm  = (unsigned short*)(ws + WS_CBM_F);
  unsigned short* cbl  = (unsigned short*)(ws + WS_CBL_F);

  // cn (= -0.5||c||^2) + loss zero (safe: outside H region)
  prep_cn<<<dim3(32), dim3(256), 0, stream>>>(cbooks, cn, loss_acc);

  // Encoder (fp32): H = relu(bands@W1+b1); z_e = H@W2+b2 (enc2 BK=32)
  gemm_f32<128, 8, 8, 16, true ><<<dim3(HIDDEN / 128, NROWS / 128), dim3(256), 0, stream>>>(
      bands, enc_w1, enc_b1, H, NROWS, HIDDEN, NBANDS);
  gemm_f32<64, 4, 8, 32, false><<<dim3(LATENT / 64, NROWS / 128), dim3(256), 0, stream>>>(
      H, enc_w2, enc_b2, z_e, NROWS, LATENT, HIDDEN);

  // Decoder weights -> transposed bf16; codebook -> 3-way bf16 split
  // (H is dead now; overlays are safe)
  prep_wT<<<dim3(208), dim3(256), 0, stream>>>(
      dec_w1, dec_w2, cbooks, w1bT, w2bT, cbh, cbm, cbl);

  // VQ on the matrix pipe (fp32-class accuracy via 6-MFMA split)
  vq_mfma<<<dim3(NROWS / 128, GQ), dim3(256), 0, stream>>>(
      z_e, cbooks, cn, cbh, cbm, cbl, z_q, zqb, idx_f, loss_acc);

  // Decoder (bf16 MFMA, transposed-weight staging); dec1 finalizes loss
  gemm_bf16_mfma<32, true, true ><<<dim3(HIDDEN / 64, NROWS / 128), dim3(256), 0, stream>>>(
      zqb, w1bT, dec_b1, (void*)h2bf, NROWS, HIDDEN, LATENT, loss_acc, loss_out);
  gemm_bf16_mfma<16, false, false><<<dim3(NBANDS / 64, NROWS / 64), dim3(256), 0, stream>>>(
      h2bf, w2bT, dec_b2, (void*)bands_hat, NROWS, NBANDS, HIDDEN, loss_acc, loss_out);
}